// Round 1
// baseline (602.023 us; speedup 1.0000x reference)
//
#include <hip/hip_runtime.h>
#include <hip/hip_bf16.h>

#define N_NODES  10000
#define N_EDGES  64000
#define N_GRAPHS 64
#define HID      64

__device__ __forceinline__ float lrelu(float v){ return v > 0.f ? v : 0.01f*v; }

// out[n, 0..63] = act(in[n, 0..K-1] @ w[K,64] (+ b))
// ACT: 0 = none, 1 = relu, 2 = leaky relu(0.01)
template<int K, int ACT>
__global__ void lin64_kernel(const float* __restrict__ in, const float* __restrict__ w,
                             const float* __restrict__ b, float* __restrict__ out, int N){
    int m = threadIdx.x;                       // 0..63 output col
    int n = blockIdx.x * 4 + threadIdx.y;      // node/edge row
    if (n >= N) return;
    float acc = b ? b[m] : 0.f;
    const float* row = in + (size_t)n * K;
    #pragma unroll 8
    for (int k = 0; k < K; ++k) acc += row[k] * w[k * 64 + m];
    if (ACT == 1) acc = fmaxf(acc, 0.f);
    if (ACT == 2) acc = lrelu(acc);
    out[(size_t)n * 64 + m] = acc;
}

// G[n, k*64+o] = sum_i hx[n,i] * w2[k, i*64+o]   (stored bf16)
// 16 nodes per block; w2 (1 MB) read once per block.
#define GNB 16
__global__ void gmat_kernel(const float* __restrict__ hx, const float* __restrict__ w2,
                            __hip_bfloat16* __restrict__ G, int N){
    __shared__ float hs[GNB][HID];
    int n0  = blockIdx.x * GNB;
    int tid = threadIdx.x;                     // 0..255
    for (int idx = tid; idx < GNB * HID; idx += 256){
        int nb = idx >> 6, i = idx & 63;
        int n = n0 + nb;
        hs[nb][i] = (n < N) ? hx[(size_t)n * HID + i] : 0.f;
    }
    __syncthreads();
    int o  = tid & 63;
    int kq = tid >> 6;                         // 0..3
    for (int p = 0; p < 16; ++p){
        int k = p * 4 + kq;
        float acc[GNB];
        #pragma unroll
        for (int nb = 0; nb < GNB; ++nb) acc[nb] = 0.f;
        const float* w2p = w2 + (size_t)k * 4096 + o;
        #pragma unroll 4
        for (int i = 0; i < HID; ++i){
            float wv = w2p[i * 64];
            #pragma unroll
            for (int nb = 0; nb < GNB; ++nb) acc[nb] += hs[nb][i] * wv;
        }
        #pragma unroll
        for (int nb = 0; nb < GNB; ++nb){
            int n = n0 + nb;
            if (n < N) G[(size_t)n * 4096 + k * 64 + o] = __float2bfloat16(acc[nb]);
        }
    }
}

// msg[e,o] = sum_k t[e,k]*G[src[e],k,o] + hb2[src[e],o]; atomic scatter to agg[dst]
__global__ void msg_kernel(const float* __restrict__ t, const __hip_bfloat16* __restrict__ G,
                           const float* __restrict__ hb2, const int* __restrict__ src,
                           const int* __restrict__ dst, float* __restrict__ agg){
    __shared__ float ts[4][HID];
    int o = threadIdx.x, y = threadIdx.y;
    int e = blockIdx.x * 4 + y;
    ts[y][o] = t[(size_t)e * 64 + o];
    __syncthreads();
    int s = src[e], d = dst[e];
    const __hip_bfloat16* gp = G + (size_t)s * 4096 + o;
    float acc = hb2[(size_t)s * 64 + o];
    #pragma unroll 8
    for (int k = 0; k < 64; ++k) acc += ts[y][k] * __bfloat162float(gp[k * 64]);
    atomicAdd(&agg[(size_t)d * 64 + o], acc);
}

// out[n,o] = lrelu(agg[n,o] + sum_i hx[n,i]*root[i,o] + bias[o])
__global__ void combine_kernel(const float* __restrict__ agg, const float* __restrict__ hx,
                               const float* __restrict__ root, const float* __restrict__ bias,
                               float* __restrict__ out, int N){
    int m = threadIdx.x;
    int n = blockIdx.x * 4 + threadIdx.y;
    if (n >= N) return;
    float acc = agg[(size_t)n * 64 + m] + bias[m];
    const float* row = hx + (size_t)n * 64;
    #pragma unroll 8
    for (int k = 0; k < 64; ++k) acc += row[k] * root[k * 64 + m];
    out[(size_t)n * 64 + m] = lrelu(acc);
}

__global__ void pool_kernel(const float* __restrict__ hx, const int* __restrict__ batch,
                            float* __restrict__ hg, int N){
    int m = threadIdx.x;
    int n = blockIdx.x * 4 + threadIdx.y;
    if (n >= N) return;
    atomicAdd(&hg[batch[n] * 64 + m], hx[(size_t)n * 64 + m]);
}

__global__ void head_kernel(const float* __restrict__ hg, const float* __restrict__ fc1w,
                            const float* __restrict__ fc1b, const float* __restrict__ fc2w,
                            const float* __restrict__ fc2b, float* __restrict__ out){
    int g = threadIdx.x;                       // 0..63
    const float* row = hg + g * 64;
    float h1[32];
    #pragma unroll
    for (int j = 0; j < 32; ++j){
        float a = fc1b[j];
        #pragma unroll 8
        for (int i = 0; i < 64; ++i) a += row[i] * fc1w[i * 32 + j];
        h1[j] = lrelu(a);
    }
    float o = fc2b[0];
    #pragma unroll
    for (int j = 0; j < 32; ++j) o += h1[j] * fc2w[j];
    out[g] = o;
}

extern "C" void kernel_launch(void* const* d_in, const int* in_sizes, int n_in,
                              void* d_out, int out_size, void* d_ws, size_t ws_size,
                              hipStream_t stream){
    const float* x      = (const float*)d_in[0];
    const int*   ei     = (const int*)  d_in[1];
    const float* ea     = (const float*)d_in[2];
    const int*   batch  = (const int*)  d_in[3];
    const float* nfc_w  = (const float*)d_in[4];
    const float* nfc_b  = (const float*)d_in[5];
    const float* e1w1   = (const float*)d_in[6];
    const float* e1b1   = (const float*)d_in[7];
    const float* e1w2   = (const float*)d_in[8];
    const float* e1b2   = (const float*)d_in[9];
    const float* g1root = (const float*)d_in[10];
    const float* g1bias = (const float*)d_in[11];
    const float* e2w1   = (const float*)d_in[12];
    const float* e2b1   = (const float*)d_in[13];
    const float* e2w2   = (const float*)d_in[14];
    const float* e2b2   = (const float*)d_in[15];
    const float* g2root = (const float*)d_in[16];
    const float* g2bias = (const float*)d_in[17];
    const float* fc1w   = (const float*)d_in[18];
    const float* fc1b   = (const float*)d_in[19];
    const float* fc2w   = (const float*)d_in[20];
    const float* fc2b   = (const float*)d_in[21];
    float* out = (float*)d_out;

    const int* src = ei;
    const int* dst = ei + N_EDGES;

    // workspace carve-up (all 256B-aligned sizes)
    char* ws = (char*)d_ws;
    float* hx1 = (float*)ws;               ws += (size_t)N_NODES * 64 * 4;   // 2.56 MB
    float* hx2 = (float*)ws;               ws += (size_t)N_NODES * 64 * 4;
    float* hx3 = (float*)ws;               ws += (size_t)N_NODES * 64 * 4;
    float* t   = (float*)ws;               ws += (size_t)N_EDGES * 64 * 4;   // 16.4 MB
    float* hb2 = (float*)ws;               ws += (size_t)N_NODES * 64 * 4;
    float* agg = (float*)ws;               ws += (size_t)N_NODES * 64 * 4;
    float* hg  = (float*)ws;               ws += (size_t)N_GRAPHS * 64 * 4;  // 16 KB
    __hip_bfloat16* G = (__hip_bfloat16*)ws;  // 82 MB

    dim3 blk(64, 4);

    // node FC: hx1 = lrelu(x @ nfc_w + nfc_b)
    lin64_kernel<128, 2><<<N_NODES / 4, blk, 0, stream>>>(x, nfc_w, nfc_b, hx1, N_NODES);

    // ---------- layer 1 ----------
    lin64_kernel<32, 1><<<N_EDGES / 4, blk, 0, stream>>>(ea, e1w1, e1b1, t, N_EDGES);
    lin64_kernel<64, 0><<<N_NODES / 4, blk, 0, stream>>>(hx1, e1b2, nullptr, hb2, N_NODES);
    gmat_kernel<<<(N_NODES + GNB - 1) / GNB, 256, 0, stream>>>(hx1, e1w2, G, N_NODES);
    hipMemsetAsync(agg, 0, (size_t)N_NODES * 64 * 4, stream);
    msg_kernel<<<N_EDGES / 4, blk, 0, stream>>>(t, G, hb2, src, dst, agg);
    combine_kernel<<<N_NODES / 4, blk, 0, stream>>>(agg, hx1, g1root, g1bias, hx2, N_NODES);

    // ---------- layer 2 ----------
    lin64_kernel<32, 1><<<N_EDGES / 4, blk, 0, stream>>>(ea, e2w1, e2b1, t, N_EDGES);
    lin64_kernel<64, 0><<<N_NODES / 4, blk, 0, stream>>>(hx2, e2b2, nullptr, hb2, N_NODES);
    gmat_kernel<<<(N_NODES + GNB - 1) / GNB, 256, 0, stream>>>(hx2, e2w2, G, N_NODES);
    hipMemsetAsync(agg, 0, (size_t)N_NODES * 64 * 4, stream);
    msg_kernel<<<N_EDGES / 4, blk, 0, stream>>>(t, G, hb2, src, dst, agg);
    combine_kernel<<<N_NODES / 4, blk, 0, stream>>>(agg, hx2, g2root, g2bias, hx3, N_NODES);

    // ---------- pool + head ----------
    hipMemsetAsync(hg, 0, (size_t)N_GRAPHS * 64 * 4, stream);
    pool_kernel<<<N_NODES / 4, blk, 0, stream>>>(hx3, batch, hg, N_NODES);
    head_kernel<<<1, 64, 0, stream>>>(hg, fc1w, fc1b, fc2w, fc2b, out);
}

// Round 3
// 515.256 us; speedup vs baseline: 1.1684x; 1.1684x over previous
//
#include <hip/hip_runtime.h>
#include <hip/hip_bf16.h>

#define N_NODES  10000
#define N_EDGES  64000
#define N_GRAPHS 64
#define HID      64

typedef __attribute__((ext_vector_type(8))) short short8;
typedef __attribute__((ext_vector_type(4))) float f32x4;

__device__ __forceinline__ float lrelu(float v){ return v > 0.f ? v : 0.01f*v; }

// round-to-nearest-even fp32 -> bf16 bits
__device__ __forceinline__ unsigned short f2bf(float f){
    union { float f; unsigned u; } v; v.f = f;
    unsigned r = v.u + 0x7fff + ((v.u >> 16) & 1);
    return (unsigned short)(r >> 16);
}
__device__ __forceinline__ float bf2f(unsigned short s){
    union { unsigned u; float f; } v; v.u = ((unsigned)s) << 16;
    return v.f;
}

// out[n, 0..63] = act(in[n, 0..K-1] @ w[K,64] (+ b))
// ACT: 0 = none, 1 = relu, 2 = leaky relu(0.01)
template<int K, int ACT>
__global__ void lin64_kernel(const float* __restrict__ in, const float* __restrict__ w,
                             const float* __restrict__ b, float* __restrict__ out, int N){
    int m = threadIdx.x;                       // 0..63 output col
    int n = blockIdx.x * 4 + threadIdx.y;      // node/edge row
    if (n >= N) return;
    float acc = b ? b[m] : 0.f;
    const float* row = in + (size_t)n * K;
    #pragma unroll 8
    for (int k = 0; k < K; ++k) acc += row[k] * w[k * 64 + m];
    if (ACT == 1) acc = fmaxf(acc, 0.f);
    if (ACT == 2) acc = lrelu(acc);
    out[(size_t)n * 64 + m] = acc;
}

// w2t[(k*64+o)*64 + i] = bf16(w2[k*4096 + i*64 + o])   (transpose i<->o within each k)
// k ranges over the FULL t-dim [0,64): one block per k.
__global__ void w2conv_kernel(const float* __restrict__ w2, unsigned short* __restrict__ w2t){
    __shared__ float tile[64][65];
    int k = blockIdx.x;                        // 0..63
    const float* src = w2 + (size_t)k * 4096;
    for (int idx = threadIdx.x; idx < 4096; idx += 256){
        int i = idx >> 6, o = idx & 63;
        tile[i][o] = src[idx];
    }
    __syncthreads();
    for (int idx = threadIdx.x; idx < 4096; idx += 256){
        int o = idx >> 6, i = idx & 63;
        w2t[((size_t)(k * 64 + o) << 6) + i] = f2bf(tile[i][o]);
    }
}

// G[n, k*64+o] = sum_i hx[n,i] * w2[k, i*64+o]  via bf16 MFMA, stored bf16.
// Block: 16 nodes, 256 threads = 4 waves; wave w handles output cols [w*1024, (w+1)*1024).
__global__ void gmat_mfma_kernel(const float* __restrict__ hx, const unsigned short* __restrict__ w2t,
                                 unsigned short* __restrict__ G){
    __shared__ unsigned short hsb[16][64];
    int tid = threadIdx.x;
    int n0 = blockIdx.x * 16;
    for (int idx = tid; idx < 1024; idx += 256){
        int nb = idx >> 6, i = idx & 63;
        hsb[nb][i] = f2bf(hx[(size_t)(n0 + nb) * 64 + i]);
    }
    __syncthreads();
    int wid = tid >> 6;                        // wave 0..3
    int l   = tid & 63;
    int m16 = l & 15;                          // A row / B col / D col index
    int grp = l >> 4;                          // k-group 0..3
    // A fragments (same for all 64 col-tiles of this wave): i = grp*8 + j (+32)
    short8 a0 = *(const short8*)&hsb[m16][grp * 8];
    short8 a1 = *(const short8*)&hsb[m16][32 + grp * 8];
    for (int t = 0; t < 64; ++t){
        int c0 = wid * 1024 + t * 16;
        const unsigned short* bp = w2t + ((size_t)(c0 + m16) << 6) + grp * 8;
        short8 b0 = *(const short8*)bp;
        short8 b1 = *(const short8*)(bp + 32);
        f32x4 acc = {0.f, 0.f, 0.f, 0.f};
        acc = __builtin_amdgcn_mfma_f32_16x16x32_bf16(a0, b0, acc, 0, 0, 0);
        acc = __builtin_amdgcn_mfma_f32_16x16x32_bf16(a1, b1, acc, 0, 0, 0);
        int dcol = c0 + m16;                   // col = lane&15
        #pragma unroll
        for (int r = 0; r < 4; ++r){
            int drow = grp * 4 + r;            // row = (lane>>4)*4 + reg
            G[((size_t)(n0 + drow) << 12) + dcol] = f2bf(acc[r]);
        }
    }
}

// msg[e,o] = sum_k t[e,k]*G[src[e],k,o] + hb2[src[e],o]; atomic scatter to agg[dst]
// Exact zero-skip: relu makes ~50% of t zero; skip is wave-uniform (wave = 1 edge).
__global__ void msg_kernel(const float* __restrict__ t, const unsigned short* __restrict__ G,
                           const float* __restrict__ hb2, const int* __restrict__ src,
                           const int* __restrict__ dst, float* __restrict__ agg){
    __shared__ float ts[4][HID];
    int o = threadIdx.x, y = threadIdx.y;
    int e = blockIdx.x * 4 + y;
    float tv = t[(size_t)e * 64 + o];
    ts[y][o] = tv;
    unsigned long long mask = __ballot(tv != 0.f);   // bit k = (t[e,k] != 0)
    __syncthreads();
    int s = src[e], d = dst[e];
    const unsigned short* gp = G + ((size_t)s << 12) + o;
    float acc = hb2[((size_t)s << 6) + o];
    while (mask){
        int k = __ffsll((long long)mask) - 1;
        mask &= mask - 1;
        acc += ts[y][k] * bf2f(gp[(size_t)k << 6]);
    }
    atomicAdd(&agg[((size_t)d << 6) + o], acc);
}

// out[n,o] = lrelu(agg[n,o] + sum_i hx[n,i]*root[i,o] + bias[o])
__global__ void combine_kernel(const float* __restrict__ agg, const float* __restrict__ hx,
                               const float* __restrict__ root, const float* __restrict__ bias,
                               float* __restrict__ out, int N){
    int m = threadIdx.x;
    int n = blockIdx.x * 4 + threadIdx.y;
    if (n >= N) return;
    float acc = agg[(size_t)n * 64 + m] + bias[m];
    const float* row = hx + (size_t)n * 64;
    #pragma unroll 8
    for (int k = 0; k < 64; ++k) acc += row[k] * root[k * 64 + m];
    out[(size_t)n * 64 + m] = lrelu(acc);
}

__global__ void pool_kernel(const float* __restrict__ hx, const int* __restrict__ batch,
                            float* __restrict__ hg, int N){
    int m = threadIdx.x;
    int n = blockIdx.x * 4 + threadIdx.y;
    if (n >= N) return;
    atomicAdd(&hg[batch[n] * 64 + m], hx[(size_t)n * 64 + m]);
}

__global__ void head_kernel(const float* __restrict__ hg, const float* __restrict__ fc1w,
                            const float* __restrict__ fc1b, const float* __restrict__ fc2w,
                            const float* __restrict__ fc2b, float* __restrict__ out){
    int g = threadIdx.x;                       // 0..63
    const float* row = hg + g * 64;
    float h1[32];
    #pragma unroll
    for (int j = 0; j < 32; ++j){
        float a = fc1b[j];
        #pragma unroll 8
        for (int i = 0; i < 64; ++i) a += row[i] * fc1w[i * 32 + j];
        h1[j] = lrelu(a);
    }
    float o = fc2b[0];
    #pragma unroll
    for (int j = 0; j < 32; ++j) o += h1[j] * fc2w[j];
    out[g] = o;
}

extern "C" void kernel_launch(void* const* d_in, const int* in_sizes, int n_in,
                              void* d_out, int out_size, void* d_ws, size_t ws_size,
                              hipStream_t stream){
    const float* x      = (const float*)d_in[0];
    const int*   ei     = (const int*)  d_in[1];
    const float* ea     = (const float*)d_in[2];
    const int*   batch  = (const int*)  d_in[3];
    const float* nfc_w  = (const float*)d_in[4];
    const float* nfc_b  = (const float*)d_in[5];
    const float* e1w1   = (const float*)d_in[6];
    const float* e1b1   = (const float*)d_in[7];
    const float* e1w2   = (const float*)d_in[8];
    const float* e1b2   = (const float*)d_in[9];
    const float* g1root = (const float*)d_in[10];
    const float* g1bias = (const float*)d_in[11];
    const float* e2w1   = (const float*)d_in[12];
    const float* e2b1   = (const float*)d_in[13];
    const float* e2w2   = (const float*)d_in[14];
    const float* e2b2   = (const float*)d_in[15];
    const float* g2root = (const float*)d_in[16];
    const float* g2bias = (const float*)d_in[17];
    const float* fc1w   = (const float*)d_in[18];
    const float* fc1b   = (const float*)d_in[19];
    const float* fc2w   = (const float*)d_in[20];
    const float* fc2b   = (const float*)d_in[21];
    float* out = (float*)d_out;

    const int* src = ei;
    const int* dst = ei + N_EDGES;

    // workspace carve-up (all 256B-aligned sizes)
    char* ws = (char*)d_ws;
    float* hx1 = (float*)ws;               ws += (size_t)N_NODES * 64 * 4;   // 2.56 MB
    float* hx2 = (float*)ws;               ws += (size_t)N_NODES * 64 * 4;
    float* t   = (float*)ws;               ws += (size_t)N_EDGES * 64 * 4;   // 16.4 MB
    float* hb2 = (float*)ws;               ws += (size_t)N_NODES * 64 * 4;
    float* agg = (float*)ws;               ws += (size_t)N_NODES * 64 * 4;
    float* hg  = (float*)ws;               ws += (size_t)N_GRAPHS * 64 * 4;  // 16 KB
    unsigned short* w2t = (unsigned short*)ws; ws += (size_t)64 * 64 * 64 * 2; // 512 KB (4096 rows x 64)
    unsigned short* G = (unsigned short*)ws;  // 82 MB
    float* hx3 = hx1;   // hx1 dead after layer-1 combine; reuse for hx3

    dim3 blk(64, 4);

    // node FC: hx1 = lrelu(x @ nfc_w + nfc_b)
    lin64_kernel<128, 2><<<N_NODES / 4, blk, 0, stream>>>(x, nfc_w, nfc_b, hx1, N_NODES);

    // ---------- layer 1 ----------
    lin64_kernel<32, 1><<<N_EDGES / 4, blk, 0, stream>>>(ea, e1w1, e1b1, t, N_EDGES);
    lin64_kernel<64, 0><<<N_NODES / 4, blk, 0, stream>>>(hx1, e1b2, nullptr, hb2, N_NODES);
    w2conv_kernel<<<64, 256, 0, stream>>>(e1w2, w2t);
    gmat_mfma_kernel<<<N_NODES / 16, 256, 0, stream>>>(hx1, w2t, G);
    hipMemsetAsync(agg, 0, (size_t)N_NODES * 64 * 4, stream);
    msg_kernel<<<N_EDGES / 4, blk, 0, stream>>>(t, G, hb2, src, dst, agg);
    combine_kernel<<<N_NODES / 4, blk, 0, stream>>>(agg, hx1, g1root, g1bias, hx2, N_NODES);

    // ---------- layer 2 ----------
    lin64_kernel<32, 1><<<N_EDGES / 4, blk, 0, stream>>>(ea, e2w1, e2b1, t, N_EDGES);
    lin64_kernel<64, 0><<<N_NODES / 4, blk, 0, stream>>>(hx2, e2b2, nullptr, hb2, N_NODES);
    w2conv_kernel<<<64, 256, 0, stream>>>(e2w2, w2t);
    gmat_mfma_kernel<<<N_NODES / 16, 256, 0, stream>>>(hx2, w2t, G);
    hipMemsetAsync(agg, 0, (size_t)N_NODES * 64 * 4, stream);
    msg_kernel<<<N_EDGES / 4, blk, 0, stream>>>(t, G, hb2, src, dst, agg);
    combine_kernel<<<N_NODES / 4, blk, 0, stream>>>(agg, hx2, g2root, g2bias, hx3, N_NODES);

    // ---------- pool + head ----------
    hipMemsetAsync(hg, 0, (size_t)N_GRAPHS * 64 * 4, stream);
    pool_kernel<<<N_NODES / 4, blk, 0, stream>>>(hx3, batch, hg, N_NODES);
    head_kernel<<<1, 64, 0, stream>>>(hg, fc1w, fc1b, fc2w, fc2b, out);
}

// Round 4
// 397.001 us; speedup vs baseline: 1.5164x; 1.2979x over previous
//
#include <hip/hip_runtime.h>
#include <hip/hip_bf16.h>

#define N_NODES  10000
#define N_EDGES  64000
#define N_GRAPHS 64
#define HID      64

typedef __attribute__((ext_vector_type(8))) short short8;
typedef __attribute__((ext_vector_type(4))) float f32x4;

__device__ __forceinline__ float lrelu(float v){ return v > 0.f ? v : 0.01f*v; }

// round-to-nearest-even fp32 -> bf16 bits
__device__ __forceinline__ unsigned short f2bf(float f){
    union { float f; unsigned u; } v; v.f = f;
    unsigned r = v.u + 0x7fff + ((v.u >> 16) & 1);
    return (unsigned short)(r >> 16);
}
__device__ __forceinline__ float bf2f(unsigned short s){
    union { unsigned u; float f; } v; v.u = ((unsigned)s) << 16;
    return v.f;
}

// out[n, 0..63] = act(in[n, 0..K-1] @ w[K,64] (+ b))
// ACT: 0 = none, 1 = relu, 2 = leaky relu(0.01)
template<int K, int ACT>
__global__ void lin64_kernel(const float* __restrict__ in, const float* __restrict__ w,
                             const float* __restrict__ b, float* __restrict__ out, int N){
    int m = threadIdx.x;                       // 0..63 output col
    int n = blockIdx.x * 4 + threadIdx.y;      // node/edge row
    if (n >= N) return;
    float acc = b ? b[m] : 0.f;
    const float* row = in + (size_t)n * K;
    #pragma unroll 8
    for (int k = 0; k < K; ++k) acc += row[k] * w[k * 64 + m];
    if (ACT == 1) acc = fmaxf(acc, 0.f);
    if (ACT == 2) acc = lrelu(acc);
    out[(size_t)n * 64 + m] = acc;
}

// w2t[(k*64+o)*64 + i] = bf16(w2[k*4096 + i*64 + o])   (transpose i<->o within each k)
__global__ void w2conv_kernel(const float* __restrict__ w2, unsigned short* __restrict__ w2t){
    __shared__ float tile[64][65];
    int k = blockIdx.x;                        // 0..63
    const float* src = w2 + (size_t)k * 4096;
    for (int idx = threadIdx.x; idx < 4096; idx += 256){
        int i = idx >> 6, o = idx & 63;
        tile[i][o] = src[idx];
    }
    __syncthreads();
    for (int idx = threadIdx.x; idx < 4096; idx += 256){
        int o = idx >> 6, i = idx & 63;
        w2t[((size_t)(k * 64 + o) << 6) + i] = f2bf(tile[i][o]);
    }
}

// G[n, k*64+o] = sum_i hx[n,i] * w2[k, i*64+o]  via bf16 MFMA, stored bf16.
__global__ void gmat_mfma_kernel(const float* __restrict__ hx, const unsigned short* __restrict__ w2t,
                                 unsigned short* __restrict__ G){
    __shared__ unsigned short hsb[16][64];
    int tid = threadIdx.x;
    int n0 = blockIdx.x * 16;
    for (int idx = tid; idx < 1024; idx += 256){
        int nb = idx >> 6, i = idx & 63;
        hsb[nb][i] = f2bf(hx[(size_t)(n0 + nb) * 64 + i]);
    }
    __syncthreads();
    int wid = tid >> 6;                        // wave 0..3
    int l   = tid & 63;
    int m16 = l & 15;                          // A row / B col / D col index
    int grp = l >> 4;                          // k-group 0..3
    short8 a0 = *(const short8*)&hsb[m16][grp * 8];
    short8 a1 = *(const short8*)&hsb[m16][32 + grp * 8];
    for (int t = 0; t < 64; ++t){
        int c0 = wid * 1024 + t * 16;
        const unsigned short* bp = w2t + ((size_t)(c0 + m16) << 6) + grp * 8;
        short8 b0 = *(const short8*)bp;
        short8 b1 = *(const short8*)(bp + 32);
        f32x4 acc = {0.f, 0.f, 0.f, 0.f};
        acc = __builtin_amdgcn_mfma_f32_16x16x32_bf16(a0, b0, acc, 0, 0, 0);
        acc = __builtin_amdgcn_mfma_f32_16x16x32_bf16(a1, b1, acc, 0, 0, 0);
        int dcol = c0 + m16;                   // col = lane&15
        #pragma unroll
        for (int r = 0; r < 4; ++r){
            int drow = grp * 4 + r;            // row = (lane>>4)*4 + reg
            G[((size_t)(n0 + drow) << 12) + dcol] = f2bf(acc[r]);
        }
    }
}

// ---------------- CSR build (by src), built once, reused by both layers ----------------
__global__ void csr_count_kernel(const int* __restrict__ src, int* __restrict__ counts){
    int e = blockIdx.x * 256 + threadIdx.x;
    if (e < N_EDGES) atomicAdd(&counts[src[e]], 1);
}

__global__ void csr_scan_kernel(const int* __restrict__ counts, int* __restrict__ rowptr){
    __shared__ int part[256];
    int tid = threadIdx.x;
    const int CH = (N_NODES + 255) / 256;      // 40
    int base = tid * CH, s = 0;
    for (int i = 0; i < CH; ++i){ int idx = base + i; if (idx < N_NODES) s += counts[idx]; }
    part[tid] = s; __syncthreads();
    for (int off = 1; off < 256; off <<= 1){
        int v = (tid >= off) ? part[tid - off] : 0;
        __syncthreads();
        part[tid] += v;
        __syncthreads();
    }
    int run = part[tid] - s;                   // exclusive prefix of this chunk
    for (int i = 0; i < CH; ++i){ int idx = base + i; if (idx < N_NODES){ rowptr[idx] = run; run += counts[idx]; } }
    if (tid == 255) rowptr[N_NODES] = run;
}

__global__ void csr_scatter_kernel(const int* __restrict__ src, const int* __restrict__ dst,
                                   const int* __restrict__ rowptr, int* __restrict__ cursor,
                                   int* __restrict__ eidx, int* __restrict__ dsts){
    int e = blockIdx.x * 256 + threadIdx.x;
    if (e >= N_EDGES) return;
    int s = src[e];
    int j = rowptr[s] + atomicAdd(&cursor[s], 1);
    eidx[j] = e; dsts[j] = dst[e];
}

// ---------------- msg, grouped by src node: G row streamed exactly once ----------------
// 1 wave per node. lane o keeps G[s,:,o] in registers; per edge, t row is LDS-broadcast.
__global__ void __launch_bounds__(64) msg_csr_kernel(
        const float* __restrict__ t, const unsigned short* __restrict__ G,
        const float* __restrict__ hb2, const int* __restrict__ rowptr,
        const int* __restrict__ eidx, const int* __restrict__ dsts,
        float* __restrict__ agg){
    int s = blockIdx.x;
    int o = threadIdx.x;
    __shared__ float ts[64];
    int r0 = rowptr[s], r1 = rowptr[s + 1];
    if (r0 == r1) return;                      // isolated node: agg row stays 0
    const unsigned short* gp = G + ((size_t)s << 12) + o;
    float g[64];
    #pragma unroll
    for (int k = 0; k < 64; ++k) g[k] = bf2f(gp[k << 6]);   // coalesced 128B/wave per k
    float hb = hb2[((size_t)s << 6) + o];
    for (int j = r0; j < r1; ++j){
        int e = eidx[j];
        ts[o] = t[((size_t)e << 6) + o];
        __syncthreads();
        float acc = hb;
        #pragma unroll
        for (int k = 0; k < 64; k += 4){
            float4 tv = *(const float4*)&ts[k];            // LDS broadcast read
            acc += tv.x * g[k] + tv.y * g[k+1] + tv.z * g[k+2] + tv.w * g[k+3];
        }
        atomicAdd(&agg[((size_t)dsts[j] << 6) + o], acc);
        __syncthreads();
    }
}

// out[n,o] = lrelu(agg[n,o] + sum_i hx[n,i]*root[i,o] + bias[o])
__global__ void combine_kernel(const float* __restrict__ agg, const float* __restrict__ hx,
                               const float* __restrict__ root, const float* __restrict__ bias,
                               float* __restrict__ out, int N){
    int m = threadIdx.x;
    int n = blockIdx.x * 4 + threadIdx.y;
    if (n >= N) return;
    float acc = agg[(size_t)n * 64 + m] + bias[m];
    const float* row = hx + (size_t)n * 64;
    #pragma unroll 8
    for (int k = 0; k < 64; ++k) acc += row[k] * root[k * 64 + m];
    out[(size_t)n * 64 + m] = lrelu(acc);
}

__global__ void pool_kernel(const float* __restrict__ hx, const int* __restrict__ batch,
                            float* __restrict__ hg, int N){
    int m = threadIdx.x;
    int n = blockIdx.x * 4 + threadIdx.y;
    if (n >= N) return;
    atomicAdd(&hg[batch[n] * 64 + m], hx[(size_t)n * 64 + m]);
}

__global__ void head_kernel(const float* __restrict__ hg, const float* __restrict__ fc1w,
                            const float* __restrict__ fc1b, const float* __restrict__ fc2w,
                            const float* __restrict__ fc2b, float* __restrict__ out){
    int g = threadIdx.x;                       // 0..63
    const float* row = hg + g * 64;
    float h1[32];
    #pragma unroll
    for (int j = 0; j < 32; ++j){
        float a = fc1b[j];
        #pragma unroll 8
        for (int i = 0; i < 64; ++i) a += row[i] * fc1w[i * 32 + j];
        h1[j] = lrelu(a);
    }
    float o = fc2b[0];
    #pragma unroll
    for (int j = 0; j < 32; ++j) o += h1[j] * fc2w[j];
    out[g] = o;
}

extern "C" void kernel_launch(void* const* d_in, const int* in_sizes, int n_in,
                              void* d_out, int out_size, void* d_ws, size_t ws_size,
                              hipStream_t stream){
    const float* x      = (const float*)d_in[0];
    const int*   ei     = (const int*)  d_in[1];
    const float* ea     = (const float*)d_in[2];
    const int*   batch  = (const int*)  d_in[3];
    const float* nfc_w  = (const float*)d_in[4];
    const float* nfc_b  = (const float*)d_in[5];
    const float* e1w1   = (const float*)d_in[6];
    const float* e1b1   = (const float*)d_in[7];
    const float* e1w2   = (const float*)d_in[8];
    const float* e1b2   = (const float*)d_in[9];
    const float* g1root = (const float*)d_in[10];
    const float* g1bias = (const float*)d_in[11];
    const float* e2w1   = (const float*)d_in[12];
    const float* e2b1   = (const float*)d_in[13];
    const float* e2w2   = (const float*)d_in[14];
    const float* e2b2   = (const float*)d_in[15];
    const float* g2root = (const float*)d_in[16];
    const float* g2bias = (const float*)d_in[17];
    const float* fc1w   = (const float*)d_in[18];
    const float* fc1b   = (const float*)d_in[19];
    const float* fc2w   = (const float*)d_in[20];
    const float* fc2b   = (const float*)d_in[21];
    float* out = (float*)d_out;

    const int* src = ei;
    const int* dst = ei + N_EDGES;

    // workspace carve-up
    char* ws = (char*)d_ws;
    float* hx1 = (float*)ws;               ws += (size_t)N_NODES * 64 * 4;   // 2.56 MB
    float* hx2 = (float*)ws;               ws += (size_t)N_NODES * 64 * 4;
    float* t   = (float*)ws;               ws += (size_t)N_EDGES * 64 * 4;   // 16.4 MB
    float* hb2 = (float*)ws;               ws += (size_t)N_NODES * 64 * 4;
    float* agg = (float*)ws;               ws += (size_t)N_NODES * 64 * 4;
    float* hg  = (float*)ws;               ws += (size_t)N_GRAPHS * 64 * 4;  // 16 KB
    unsigned short* w2t = (unsigned short*)ws; ws += (size_t)64 * 64 * 64 * 2; // 512 KB
    int* counts = (int*)ws;                ws += (size_t)10240 * 4;          // also reused as cursor
    int* rowptr = (int*)ws;                ws += (size_t)10240 * 4;
    int* eidx   = (int*)ws;                ws += (size_t)N_EDGES * 4;
    int* dsts   = (int*)ws;                ws += (size_t)N_EDGES * 4;
    unsigned short* G = (unsigned short*)ws;  // 82 MB
    float* hx3 = hx1;   // hx1 dead after layer-1 combine; reuse

    dim3 blk(64, 4);

    // ---------- CSR by src (built once, reused by both layers) ----------
    hipMemsetAsync(counts, 0, (size_t)N_NODES * 4, stream);
    csr_count_kernel<<<N_EDGES / 256, 256, 0, stream>>>(src, counts);
    csr_scan_kernel<<<1, 256, 0, stream>>>(counts, rowptr);
    hipMemsetAsync(counts, 0, (size_t)N_NODES * 4, stream);   // reuse as cursor
    csr_scatter_kernel<<<N_EDGES / 256, 256, 0, stream>>>(src, dst, rowptr, counts, eidx, dsts);

    // node FC: hx1 = lrelu(x @ nfc_w + nfc_b)
    lin64_kernel<128, 2><<<N_NODES / 4, blk, 0, stream>>>(x, nfc_w, nfc_b, hx1, N_NODES);

    // ---------- layer 1 ----------
    lin64_kernel<32, 1><<<N_EDGES / 4, blk, 0, stream>>>(ea, e1w1, e1b1, t, N_EDGES);
    lin64_kernel<64, 0><<<N_NODES / 4, blk, 0, stream>>>(hx1, e1b2, nullptr, hb2, N_NODES);
    w2conv_kernel<<<64, 256, 0, stream>>>(e1w2, w2t);
    gmat_mfma_kernel<<<N_NODES / 16, 256, 0, stream>>>(hx1, w2t, G);
    hipMemsetAsync(agg, 0, (size_t)N_NODES * 64 * 4, stream);
    msg_csr_kernel<<<N_NODES, 64, 0, stream>>>(t, G, hb2, rowptr, eidx, dsts, agg);
    combine_kernel<<<N_NODES / 4, blk, 0, stream>>>(agg, hx1, g1root, g1bias, hx2, N_NODES);

    // ---------- layer 2 ----------
    lin64_kernel<32, 1><<<N_EDGES / 4, blk, 0, stream>>>(ea, e2w1, e2b1, t, N_EDGES);
    lin64_kernel<64, 0><<<N_NODES / 4, blk, 0, stream>>>(hx2, e2b2, nullptr, hb2, N_NODES);
    w2conv_kernel<<<64, 256, 0, stream>>>(e2w2, w2t);
    gmat_mfma_kernel<<<N_NODES / 16, 256, 0, stream>>>(hx2, w2t, G);
    hipMemsetAsync(agg, 0, (size_t)N_NODES * 64 * 4, stream);
    msg_csr_kernel<<<N_NODES, 64, 0, stream>>>(t, G, hb2, rowptr, eidx, dsts, agg);
    combine_kernel<<<N_NODES / 4, blk, 0, stream>>>(agg, hx2, g2root, g2bias, hx3, N_NODES);

    // ---------- pool + head ----------
    hipMemsetAsync(hg, 0, (size_t)N_GRAPHS * 64 * 4, stream);
    pool_kernel<<<N_NODES / 4, blk, 0, stream>>>(hx3, batch, hg, N_NODES);
    head_kernel<<<1, 64, 0, stream>>>(hg, fc1w, fc1b, fc2w, fc2b, out);
}

// Round 5
// 382.558 us; speedup vs baseline: 1.5737x; 1.0378x over previous
//
#include <hip/hip_runtime.h>
#include <hip/hip_bf16.h>

#define N_NODES  10000
#define N_EDGES  64000
#define N_GRAPHS 64
#define HID      64

typedef __attribute__((ext_vector_type(8))) short short8;
typedef __attribute__((ext_vector_type(4))) float f32x4;

__device__ __forceinline__ float lrelu(float v){ return v > 0.f ? v : 0.01f*v; }

// round-to-nearest-even fp32 -> bf16 bits
__device__ __forceinline__ unsigned short f2bf(float f){
    union { float f; unsigned u; } v; v.f = f;
    unsigned r = v.u + 0x7fff + ((v.u >> 16) & 1);
    return (unsigned short)(r >> 16);
}
__device__ __forceinline__ float bf2f(unsigned short s){
    union { unsigned u; float f; } v; v.u = ((unsigned)s) << 16;
    return v.f;
}

// out[n, 0..63] = act(in[n, 0..K-1] @ w[K,64] (+ b));  ACT: 0 none, 1 relu, 2 lrelu
template<int K, int ACT>
__global__ void lin64_kernel(const float* __restrict__ in, const float* __restrict__ w,
                             const float* __restrict__ b, float* __restrict__ out, int N){
    int m = threadIdx.x;
    int n = blockIdx.x * 4 + threadIdx.y;
    if (n >= N) return;
    float acc = b ? b[m] : 0.f;
    const float* row = in + (size_t)n * K;
    #pragma unroll 8
    for (int k = 0; k < K; ++k) acc += row[k] * w[k * 64 + m];
    if (ACT == 1) acc = fmaxf(acc, 0.f);
    if (ACT == 2) acc = lrelu(acc);
    out[(size_t)n * 64 + m] = acc;
}

// gathered variant: row j comes from in[gidx[j]]  (produces CSR-ordered t)
template<int K, int ACT>
__global__ void lin64g_kernel(const float* __restrict__ in, const int* __restrict__ gidx,
                              const float* __restrict__ w, const float* __restrict__ b,
                              float* __restrict__ out, int N){
    int m = threadIdx.x;
    int n = blockIdx.x * 4 + threadIdx.y;
    if (n >= N) return;
    const float* row = in + (size_t)gidx[n] * K;
    float acc = b[m];
    #pragma unroll 8
    for (int k = 0; k < K; ++k) acc += row[k] * w[k * 64 + m];
    if (ACT == 1) acc = fmaxf(acc, 0.f);
    if (ACT == 2) acc = lrelu(acc);
    out[(size_t)n * 64 + m] = acc;
}

// w2t[(k*64+o)*64 + i] = bf16(w2[k*4096 + i*64 + o])
__global__ void w2conv_kernel(const float* __restrict__ w2, unsigned short* __restrict__ w2t){
    __shared__ float tile[64][65];
    int k = blockIdx.x;                        // 0..63
    const float* src = w2 + (size_t)k * 4096;
    for (int idx = threadIdx.x; idx < 4096; idx += 256){
        int i = idx >> 6, o = idx & 63;
        tile[i][o] = src[idx];
    }
    __syncthreads();
    for (int idx = threadIdx.x; idx < 4096; idx += 256){
        int o = idx >> 6, i = idx & 63;
        w2t[((size_t)(k * 64 + o) << 6) + i] = f2bf(tile[i][o]);
    }
}

// G[n, col] = sum_i hx[n,i] * w2t[col, i]  via bf16 MFMA with SWAPPED operands:
// A = w2t tile (16 cols x 32 i), B = hx^T (32 i x 16 nodes)
// => D col(lane&15) = node, D rows = 4 consecutive G-cols per lane -> uint2 store.
// grid (625, 4): block handles 16 nodes x 1024 cols; 4 waves x 16 col-tiles.
__global__ void gmat_mfma_kernel(const float* __restrict__ hx, const unsigned short* __restrict__ w2t,
                                 unsigned short* __restrict__ G){
    __shared__ unsigned short hsb[16][64];
    int tid = threadIdx.x;
    int n0 = blockIdx.x * 16;
    for (int idx = tid; idx < 1024; idx += 256){
        int nb = idx >> 6, i = idx & 63;
        hsb[nb][i] = f2bf(hx[(size_t)(n0 + nb) * 64 + i]);
    }
    __syncthreads();
    int wid = tid >> 6;                        // wave 0..3
    int l   = tid & 63;
    int m16 = l & 15;
    int grp = l >> 4;                          // 0..3
    // B-operand (node features): lane provides B[i=grp*8+j][node=m16]
    short8 b0 = *(const short8*)&hsb[m16][grp * 8];
    short8 b1 = *(const short8*)&hsb[m16][32 + grp * 8];
    int cbase = blockIdx.y * 1024 + wid * 256;
    unsigned short* gout = G + ((size_t)(n0 + m16) << 12);
    for (int t = 0; t < 16; ++t){
        int c0 = cbase + t * 16;
        // A-operand (weights): lane provides A[col=c0+m16][i=grp*8+j]
        const unsigned short* ap = w2t + ((size_t)(c0 + m16) << 6) + grp * 8;
        short8 a0 = *(const short8*)ap;
        short8 a1 = *(const short8*)(ap + 32);
        f32x4 acc = {0.f, 0.f, 0.f, 0.f};
        acc = __builtin_amdgcn_mfma_f32_16x16x32_bf16(a0, b0, acc, 0, 0, 0);
        acc = __builtin_amdgcn_mfma_f32_16x16x32_bf16(a1, b1, acc, 0, 0, 0);
        // lane holds G[n0+m16][c0+grp*4 + (0..3)]  -> pack 4 bf16 = 8 B store
        unsigned p0 = (unsigned)f2bf(acc[0]) | ((unsigned)f2bf(acc[1]) << 16);
        unsigned p1 = (unsigned)f2bf(acc[2]) | ((unsigned)f2bf(acc[3]) << 16);
        uint2 pk; pk.x = p0; pk.y = p1;
        *(uint2*)(gout + c0 + grp * 4) = pk;
    }
}

// ---------------- CSR build (by src), built once, reused by both layers ----------------
__global__ void csr_count_kernel(const int* __restrict__ src, int* __restrict__ counts){
    int e = blockIdx.x * 256 + threadIdx.x;
    if (e < N_EDGES) atomicAdd(&counts[src[e]], 1);
}

__global__ void csr_scan_kernel(const int* __restrict__ counts, int* __restrict__ rowptr){
    __shared__ int part[256];
    int tid = threadIdx.x;
    const int CH = (N_NODES + 255) / 256;      // 40
    int base = tid * CH, s = 0;
    for (int i = 0; i < CH; ++i){ int idx = base + i; if (idx < N_NODES) s += counts[idx]; }
    part[tid] = s; __syncthreads();
    for (int off = 1; off < 256; off <<= 1){
        int v = (tid >= off) ? part[tid - off] : 0;
        __syncthreads();
        part[tid] += v;
        __syncthreads();
    }
    int run = part[tid] - s;
    for (int i = 0; i < CH; ++i){ int idx = base + i; if (idx < N_NODES){ rowptr[idx] = run; run += counts[idx]; } }
    if (tid == 255) rowptr[N_NODES] = run;
}

__global__ void csr_scatter_kernel(const int* __restrict__ src, const int* __restrict__ dst,
                                   const int* __restrict__ rowptr, int* __restrict__ cursor,
                                   int* __restrict__ eidx, int* __restrict__ dsts){
    int e = blockIdx.x * 256 + threadIdx.x;
    if (e >= N_EDGES) return;
    int s = src[e];
    int j = rowptr[s] + atomicAdd(&cursor[s], 1);
    eidx[j] = e; dsts[j] = dst[e];
}

// ---------------- msg, grouped by src: G row streamed once, t pre-permuted ----------------
// 1 wave per node; tp is already in CSR order (row j).
__global__ void __launch_bounds__(64) msg_csr_kernel(
        const float* __restrict__ tp, const unsigned short* __restrict__ G,
        const float* __restrict__ hb2, const int* __restrict__ rowptr,
        const int* __restrict__ dsts, float* __restrict__ agg){
    int s = blockIdx.x;
    int o = threadIdx.x;
    __shared__ unsigned short gl[4096];
    __shared__ float ts[64];
    int r0 = rowptr[s], r1 = rowptr[s + 1];
    if (r0 == r1) return;                      // isolated node: agg row stays 0
    // coalesced G-row load (8 KB) via short8
    const short8* gsrc = (const short8*)(G + ((size_t)s << 12));
    short8* gld = (short8*)gl;
    #pragma unroll
    for (int i = 0; i < 8; ++i) gld[i * 64 + o] = gsrc[i * 64 + o];
    // single-wave block: LDS ops are in-order within the wave; no barrier needed
    float g[64];
    #pragma unroll
    for (int k = 0; k < 64; ++k) g[k] = bf2f(gl[k * 64 + o]);
    float hb = hb2[((size_t)s << 6) + o];
    for (int j = r0; j < r1; ++j){
        ts[o] = tp[((size_t)j << 6) + o];
        float acc = hb;
        #pragma unroll
        for (int k = 0; k < 64; k += 4){
            float4 tv = *(const float4*)&ts[k];            // LDS broadcast
            acc += tv.x * g[k] + tv.y * g[k+1] + tv.z * g[k+2] + tv.w * g[k+3];
        }
        atomicAdd(&agg[((size_t)dsts[j] << 6) + o], acc);
    }
}

// out[n,o] = lrelu(agg[n,o] + sum_i hx[n,i]*root[i,o] + bias[o])
__global__ void combine_kernel(const float* __restrict__ agg, const float* __restrict__ hx,
                               const float* __restrict__ root, const float* __restrict__ bias,
                               float* __restrict__ out, int N){
    int m = threadIdx.x;
    int n = blockIdx.x * 4 + threadIdx.y;
    if (n >= N) return;
    float acc = agg[(size_t)n * 64 + m] + bias[m];
    const float* row = hx + (size_t)n * 64;
    #pragma unroll 8
    for (int k = 0; k < 64; ++k) acc += row[k] * root[k * 64 + m];
    out[(size_t)n * 64 + m] = lrelu(acc);
}

__global__ void pool_kernel(const float* __restrict__ hx, const int* __restrict__ batch,
                            float* __restrict__ hg, int N){
    int m = threadIdx.x;
    int n = blockIdx.x * 4 + threadIdx.y;
    if (n >= N) return;
    atomicAdd(&hg[batch[n] * 64 + m], hx[(size_t)n * 64 + m]);
}

__global__ void head_kernel(const float* __restrict__ hg, const float* __restrict__ fc1w,
                            const float* __restrict__ fc1b, const float* __restrict__ fc2w,
                            const float* __restrict__ fc2b, float* __restrict__ out){
    int g = threadIdx.x;                       // 0..63
    const float* row = hg + g * 64;
    float h1[32];
    #pragma unroll
    for (int j = 0; j < 32; ++j){
        float a = fc1b[j];
        #pragma unroll 8
        for (int i = 0; i < 64; ++i) a += row[i] * fc1w[i * 32 + j];
        h1[j] = lrelu(a);
    }
    float o = fc2b[0];
    #pragma unroll
    for (int j = 0; j < 32; ++j) o += h1[j] * fc2w[j];
    out[g] = o;
}

extern "C" void kernel_launch(void* const* d_in, const int* in_sizes, int n_in,
                              void* d_out, int out_size, void* d_ws, size_t ws_size,
                              hipStream_t stream){
    const float* x      = (const float*)d_in[0];
    const int*   ei     = (const int*)  d_in[1];
    const float* ea     = (const float*)d_in[2];
    const int*   batch  = (const int*)  d_in[3];
    const float* nfc_w  = (const float*)d_in[4];
    const float* nfc_b  = (const float*)d_in[5];
    const float* e1w1   = (const float*)d_in[6];
    const float* e1b1   = (const float*)d_in[7];
    const float* e1w2   = (const float*)d_in[8];
    const float* e1b2   = (const float*)d_in[9];
    const float* g1root = (const float*)d_in[10];
    const float* g1bias = (const float*)d_in[11];
    const float* e2w1   = (const float*)d_in[12];
    const float* e2b1   = (const float*)d_in[13];
    const float* e2w2   = (const float*)d_in[14];
    const float* e2b2   = (const float*)d_in[15];
    const float* g2root = (const float*)d_in[16];
    const float* g2bias = (const float*)d_in[17];
    const float* fc1w   = (const float*)d_in[18];
    const float* fc1b   = (const float*)d_in[19];
    const float* fc2w   = (const float*)d_in[20];
    const float* fc2b   = (const float*)d_in[21];
    float* out = (float*)d_out;

    const int* src = ei;
    const int* dst = ei + N_EDGES;

    // workspace carve-up
    char* ws = (char*)d_ws;
    float* hx1 = (float*)ws;               ws += (size_t)N_NODES * 64 * 4;   // 2.56 MB
    float* hx2 = (float*)ws;               ws += (size_t)N_NODES * 64 * 4;
    float* tp  = (float*)ws;               ws += (size_t)N_EDGES * 64 * 4;   // 16.4 MB (CSR order)
    float* hb2 = (float*)ws;               ws += (size_t)N_NODES * 64 * 4;
    float* agg = (float*)ws;               ws += (size_t)N_NODES * 64 * 4;
    float* hg  = (float*)ws;               ws += (size_t)N_GRAPHS * 64 * 4;  // 16 KB
    unsigned short* w2t = (unsigned short*)ws; ws += (size_t)64 * 64 * 64 * 2; // 512 KB
    int* counts = (int*)ws;                ws += (size_t)10240 * 4;          // reused as cursor
    int* rowptr = (int*)ws;                ws += (size_t)10240 * 4;
    int* eidx   = (int*)ws;                ws += (size_t)N_EDGES * 4;
    int* dsts   = (int*)ws;                ws += (size_t)N_EDGES * 4;
    unsigned short* G = (unsigned short*)ws;  // 82 MB
    float* hx3 = hx1;

    dim3 blk(64, 4);

    // ---------- CSR by src (once, reused) ----------
    hipMemsetAsync(counts, 0, (size_t)N_NODES * 4, stream);
    csr_count_kernel<<<N_EDGES / 256, 256, 0, stream>>>(src, counts);
    csr_scan_kernel<<<1, 256, 0, stream>>>(counts, rowptr);
    hipMemsetAsync(counts, 0, (size_t)N_NODES * 4, stream);
    csr_scatter_kernel<<<N_EDGES / 256, 256, 0, stream>>>(src, dst, rowptr, counts, eidx, dsts);

    // node FC
    lin64_kernel<128, 2><<<N_NODES / 4, blk, 0, stream>>>(x, nfc_w, nfc_b, hx1, N_NODES);

    dim3 ggrid(N_NODES / 16, 4);

    // ---------- layer 1 ----------
    lin64g_kernel<32, 1><<<N_EDGES / 4, blk, 0, stream>>>(ea, eidx, e1w1, e1b1, tp, N_EDGES);
    lin64_kernel<64, 0><<<N_NODES / 4, blk, 0, stream>>>(hx1, e1b2, nullptr, hb2, N_NODES);
    w2conv_kernel<<<64, 256, 0, stream>>>(e1w2, w2t);
    gmat_mfma_kernel<<<ggrid, 256, 0, stream>>>(hx1, w2t, G);
    hipMemsetAsync(agg, 0, (size_t)N_NODES * 64 * 4, stream);
    msg_csr_kernel<<<N_NODES, 64, 0, stream>>>(tp, G, hb2, rowptr, dsts, agg);
    combine_kernel<<<N_NODES / 4, blk, 0, stream>>>(agg, hx1, g1root, g1bias, hx2, N_NODES);

    // ---------- layer 2 ----------
    lin64g_kernel<32, 1><<<N_EDGES / 4, blk, 0, stream>>>(ea, eidx, e2w1, e2b1, tp, N_EDGES);
    lin64_kernel<64, 0><<<N_NODES / 4, blk, 0, stream>>>(hx2, e2b2, nullptr, hb2, N_NODES);
    w2conv_kernel<<<64, 256, 0, stream>>>(e2w2, w2t);
    gmat_mfma_kernel<<<ggrid, 256, 0, stream>>>(hx2, w2t, G);
    hipMemsetAsync(agg, 0, (size_t)N_NODES * 64 * 4, stream);
    msg_csr_kernel<<<N_NODES, 64, 0, stream>>>(tp, G, hb2, rowptr, dsts, agg);
    combine_kernel<<<N_NODES / 4, blk, 0, stream>>>(agg, hx2, g2root, g2bias, hx3, N_NODES);

    // ---------- pool + head ----------
    hipMemsetAsync(hg, 0, (size_t)N_GRAPHS * 64 * 4, stream);
    pool_kernel<<<N_NODES / 4, blk, 0, stream>>>(hx3, batch, hg, N_NODES);
    head_kernel<<<1, 64, 0, stream>>>(hg, fc1w, fc1b, fc2w, fc2b, out);
}

// Round 6
// 349.454 us; speedup vs baseline: 1.7228x; 1.0947x over previous
//
#include <hip/hip_runtime.h>
#include <hip/hip_bf16.h>

#define N_NODES  10000
#define N_EDGES  64000
#define N_GRAPHS 64
#define HID      64

typedef __attribute__((ext_vector_type(8))) short short8;
typedef __attribute__((ext_vector_type(4))) float f32x4;

__device__ __forceinline__ float lrelu(float v){ return v > 0.f ? v : 0.01f*v; }

// round-to-nearest-even fp32 -> bf16 bits
__device__ __forceinline__ unsigned short f2bf(float f){
    union { float f; unsigned u; } v; v.f = f;
    unsigned r = v.u + 0x7fff + ((v.u >> 16) & 1);
    return (unsigned short)(r >> 16);
}
__device__ __forceinline__ float bf2f(unsigned short s){
    union { unsigned u; float f; } v; v.u = ((unsigned)s) << 16;
    return v.f;
}

// out[n, 0..63] = act(in[n, 0..K-1] @ w[K,64] (+ b));  ACT: 0 none, 1 relu, 2 lrelu
template<int K, int ACT>
__global__ void lin64_kernel(const float* __restrict__ in, const float* __restrict__ w,
                             const float* __restrict__ b, float* __restrict__ out, int N){
    int m = threadIdx.x;
    int n = blockIdx.x * 4 + threadIdx.y;
    if (n >= N) return;
    float acc = b ? b[m] : 0.f;
    const float* row = in + (size_t)n * K;
    #pragma unroll 8
    for (int k = 0; k < K; ++k) acc += row[k] * w[k * 64 + m];
    if (ACT == 1) acc = fmaxf(acc, 0.f);
    if (ACT == 2) acc = lrelu(acc);
    out[(size_t)n * 64 + m] = acc;
}

// gathered variant: row j comes from in[gidx[j]]  (produces CSR-ordered t)
template<int K, int ACT>
__global__ void lin64g_kernel(const float* __restrict__ in, const int* __restrict__ gidx,
                              const float* __restrict__ w, const float* __restrict__ b,
                              float* __restrict__ out, int N){
    int m = threadIdx.x;
    int n = blockIdx.x * 4 + threadIdx.y;
    if (n >= N) return;
    const float* row = in + (size_t)gidx[n] * K;
    float acc = b[m];
    #pragma unroll 8
    for (int k = 0; k < K; ++k) acc += row[k] * w[k * 64 + m];
    if (ACT == 1) acc = fmaxf(acc, 0.f);
    if (ACT == 2) acc = lrelu(acc);
    out[(size_t)n * 64 + m] = acc;
}

// w2t[(k*64+o)*64 + i] = bf16(w2[k*4096 + i*64 + o]); both layers in one launch.
__global__ void w2conv_kernel(const float* __restrict__ w2a, unsigned short* __restrict__ w2ta,
                              const float* __restrict__ w2b, unsigned short* __restrict__ w2tb){
    __shared__ float tile[64][65];
    int k = blockIdx.x & 63;
    const float* src = ((blockIdx.x < 64) ? w2a : w2b) + (size_t)k * 4096;
    unsigned short* dst = (blockIdx.x < 64) ? w2ta : w2tb;
    for (int idx = threadIdx.x; idx < 4096; idx += 256){
        int i = idx >> 6, o = idx & 63;
        tile[i][o] = src[idx];
    }
    __syncthreads();
    for (int idx = threadIdx.x; idx < 4096; idx += 256){
        int o = idx >> 6, i = idx & 63;
        dst[((size_t)(k * 64 + o) << 6) + i] = f2bf(tile[i][o]);
    }
}

// G[n, col] = sum_i hx[n,i] * w2t[col, i]  via swapped-operand bf16 MFMA.
// Block: 64 nodes (4 groups of 16) x 512 cols (blockIdx.y of 8). 4 waves.
// Wave wid, iter t: tile base TB = cb + t*64 + wid*16. A-frag shared by 4 node-groups.
// D staged in LDS (XOR-swizzled), flushed per 256-col half with coalesced dwordx4.
__global__ void __launch_bounds__(256) gmat_mfma_kernel(
        const float* __restrict__ hx, const unsigned short* __restrict__ w2t,
        unsigned short* __restrict__ G){
    __shared__ unsigned short stg[64 * 256];   // 32 KB: 64 rows x 256 cols (one half)
    int tid = threadIdx.x;
    int wid = tid >> 6, l = tid & 63;
    int m16 = l & 15, grp = l >> 4;
    int n0 = blockIdx.x * 64;
    int cb = blockIdx.y * 512;

    // B fragments: 4 node-groups, straight from global hx (dense 128B rows), cvt in regs
    short8 bf0[4], bf1[4];
    #pragma unroll
    for (int ng = 0; ng < 4; ++ng){
        int node = n0 + ng * 16 + m16;
        short8 b0 = {0,0,0,0,0,0,0,0}, b1 = {0,0,0,0,0,0,0,0};
        if (node < N_NODES){
            const float* hp = hx + ((size_t)node << 6) + grp * 8;
            float4 f0 = *(const float4*)(hp);
            float4 f1 = *(const float4*)(hp + 4);
            float4 f2 = *(const float4*)(hp + 32);
            float4 f3 = *(const float4*)(hp + 36);
            b0[0]=(short)f2bf(f0.x); b0[1]=(short)f2bf(f0.y); b0[2]=(short)f2bf(f0.z); b0[3]=(short)f2bf(f0.w);
            b0[4]=(short)f2bf(f1.x); b0[5]=(short)f2bf(f1.y); b0[6]=(short)f2bf(f1.z); b0[7]=(short)f2bf(f1.w);
            b1[0]=(short)f2bf(f2.x); b1[1]=(short)f2bf(f2.y); b1[2]=(short)f2bf(f2.z); b1[3]=(short)f2bf(f2.w);
            b1[4]=(short)f2bf(f3.x); b1[5]=(short)f2bf(f3.y); b1[6]=(short)f2bf(f3.z); b1[7]=(short)f2bf(f3.w);
        }
        bf0[ng] = b0; bf1[ng] = b1;
    }

    for (int h = 0; h < 2; ++h){
        #pragma unroll
        for (int tt = 0; tt < 4; ++tt){
            int t = h * 4 + tt;
            int TB = cb + t * 64 + wid * 16;
            const unsigned short* ap = w2t + ((size_t)(TB + m16) << 6) + grp * 8;
            short8 a0 = *(const short8*)ap;
            short8 a1 = *(const short8*)(ap + 32);
            int inrow = (tt * 128 + wid * 32 + grp * 8) ^ ((m16 & 7) << 4);
            #pragma unroll
            for (int ng = 0; ng < 4; ++ng){
                f32x4 acc = {0.f, 0.f, 0.f, 0.f};
                acc = __builtin_amdgcn_mfma_f32_16x16x32_bf16(a0, bf0[ng], acc, 0, 0, 0);
                acc = __builtin_amdgcn_mfma_f32_16x16x32_bf16(a1, bf1[ng], acc, 0, 0, 0);
                unsigned p0 = (unsigned)f2bf(acc[0]) | ((unsigned)f2bf(acc[1]) << 16);
                unsigned p1 = (unsigned)f2bf(acc[2]) | ((unsigned)f2bf(acc[3]) << 16);
                int row = ng * 16 + m16;
                uint2 pk; pk.x = p0; pk.y = p1;
                *(uint2*)((char*)stg + row * 512 + inrow) = pk;
            }
        }
        __syncthreads();
        // flush half-tile: 8 steps x 256 threads x 16B, coalesced 512B row segments
        #pragma unroll
        for (int s = 0; s < 8; ++s){
            int ci = s * 256 + tid;                 // 2048 chunks of 16B
            int row = ci >> 5;                      // 32 chunks per row
            int node = n0 + row;
            uint4 v = *(uint4*)((char*)stg + row * 512 + (((ci & 31) * 16) ^ ((row & 7) << 4)));
            if (node < N_NODES)
                *(uint4*)(G + ((size_t)node << 12) + cb + h * 256 + (ci & 31) * 8) = v;
        }
        __syncthreads();
    }
}

// ---------------- CSR build (by src), built once, reused by both layers ----------------
__global__ void csr_count_kernel(const int* __restrict__ src, int* __restrict__ counts){
    int e = blockIdx.x * 256 + threadIdx.x;
    if (e < N_EDGES) atomicAdd(&counts[src[e]], 1);
}

__global__ void csr_scan_kernel(const int* __restrict__ counts, int* __restrict__ rowptr){
    __shared__ int part[256];
    int tid = threadIdx.x;
    const int CH = (N_NODES + 255) / 256;      // 40
    int base = tid * CH, s = 0;
    for (int i = 0; i < CH; ++i){ int idx = base + i; if (idx < N_NODES) s += counts[idx]; }
    part[tid] = s; __syncthreads();
    for (int off = 1; off < 256; off <<= 1){
        int v = (tid >= off) ? part[tid - off] : 0;
        __syncthreads();
        part[tid] += v;
        __syncthreads();
    }
    int run = part[tid] - s;
    for (int i = 0; i < CH; ++i){ int idx = base + i; if (idx < N_NODES){ rowptr[idx] = run; run += counts[idx]; } }
    if (tid == 255) rowptr[N_NODES] = run;
}

__global__ void csr_scatter_kernel(const int* __restrict__ src, const int* __restrict__ dst,
                                   const int* __restrict__ rowptr, int* __restrict__ cursor,
                                   int* __restrict__ eidx, int* __restrict__ dsts){
    int e = blockIdx.x * 256 + threadIdx.x;
    if (e >= N_EDGES) return;
    int s = src[e];
    int j = rowptr[s] + atomicAdd(&cursor[s], 1);
    eidx[j] = e; dsts[j] = dst[e];
}

// ---------------- msg, grouped by src: G row streamed once, t pre-permuted ----------------
__global__ void __launch_bounds__(64) msg_csr_kernel(
        const float* __restrict__ tp, const unsigned short* __restrict__ G,
        const float* __restrict__ hb2, const int* __restrict__ rowptr,
        const int* __restrict__ dsts, float* __restrict__ agg){
    int s = blockIdx.x;
    int o = threadIdx.x;
    __shared__ unsigned short gl[4096];
    __shared__ float ts[64];
    int r0 = rowptr[s], r1 = rowptr[s + 1];
    if (r0 == r1) return;                      // isolated node: agg row stays 0
    const short8* gsrc = (const short8*)(G + ((size_t)s << 12));
    short8* gld = (short8*)gl;
    #pragma unroll
    for (int i = 0; i < 8; ++i) gld[i * 64 + o] = gsrc[i * 64 + o];
    float g[64];
    #pragma unroll
    for (int k = 0; k < 64; ++k) g[k] = bf2f(gl[k * 64 + o]);
    float hb = hb2[((size_t)s << 6) + o];
    for (int j = r0; j < r1; ++j){
        ts[o] = tp[((size_t)j << 6) + o];
        float acc = hb;
        #pragma unroll
        for (int k = 0; k < 64; k += 4){
            float4 tv = *(const float4*)&ts[k];            // LDS broadcast
            acc += tv.x * g[k] + tv.y * g[k+1] + tv.z * g[k+2] + tv.w * g[k+3];
        }
        atomicAdd(&agg[((size_t)dsts[j] << 6) + o], acc);
    }
}

// out[n,o] = lrelu(agg[n,o] + sum_i hx[n,i]*root[i,o] + bias[o])
__global__ void combine_kernel(const float* __restrict__ agg, const float* __restrict__ hx,
                               const float* __restrict__ root, const float* __restrict__ bias,
                               float* __restrict__ out, int N){
    int m = threadIdx.x;
    int n = blockIdx.x * 4 + threadIdx.y;
    if (n >= N) return;
    float acc = agg[(size_t)n * 64 + m] + bias[m];
    const float* row = hx + (size_t)n * 64;
    #pragma unroll 8
    for (int k = 0; k < 64; ++k) acc += row[k] * root[k * 64 + m];
    out[(size_t)n * 64 + m] = lrelu(acc);
}

__global__ void pool_kernel(const float* __restrict__ hx, const int* __restrict__ batch,
                            float* __restrict__ hg, int N){
    int m = threadIdx.x;
    int n = blockIdx.x * 4 + threadIdx.y;
    if (n >= N) return;
    atomicAdd(&hg[batch[n] * 64 + m], hx[(size_t)n * 64 + m]);
}

__global__ void head_kernel(const float* __restrict__ hg, const float* __restrict__ fc1w,
                            const float* __restrict__ fc1b, const float* __restrict__ fc2w,
                            const float* __restrict__ fc2b, float* __restrict__ out){
    int g = threadIdx.x;                       // 0..63
    const float* row = hg + g * 64;
    float h1[32];
    #pragma unroll
    for (int j = 0; j < 32; ++j){
        float a = fc1b[j];
        #pragma unroll 8
        for (int i = 0; i < 64; ++i) a += row[i] * fc1w[i * 32 + j];
        h1[j] = lrelu(a);
    }
    float o = fc2b[0];
    #pragma unroll
    for (int j = 0; j < 32; ++j) o += h1[j] * fc2w[j];
    out[g] = o;
}

extern "C" void kernel_launch(void* const* d_in, const int* in_sizes, int n_in,
                              void* d_out, int out_size, void* d_ws, size_t ws_size,
                              hipStream_t stream){
    const float* x      = (const float*)d_in[0];
    const int*   ei     = (const int*)  d_in[1];
    const float* ea     = (const float*)d_in[2];
    const int*   batch  = (const int*)  d_in[3];
    const float* nfc_w  = (const float*)d_in[4];
    const float* nfc_b  = (const float*)d_in[5];
    const float* e1w1   = (const float*)d_in[6];
    const float* e1b1   = (const float*)d_in[7];
    const float* e1w2   = (const float*)d_in[8];
    const float* e1b2   = (const float*)d_in[9];
    const float* g1root = (const float*)d_in[10];
    const float* g1bias = (const float*)d_in[11];
    const float* e2w1   = (const float*)d_in[12];
    const float* e2b1   = (const float*)d_in[13];
    const float* e2w2   = (const float*)d_in[14];
    const float* e2b2   = (const float*)d_in[15];
    const float* g2root = (const float*)d_in[16];
    const float* g2bias = (const float*)d_in[17];
    const float* fc1w   = (const float*)d_in[18];
    const float* fc1b   = (const float*)d_in[19];
    const float* fc2w   = (const float*)d_in[20];
    const float* fc2b   = (const float*)d_in[21];
    float* out = (float*)d_out;

    const int* src = ei;
    const int* dst = ei + N_EDGES;

    // workspace carve-up
    char* ws = (char*)d_ws;
    float* hx1 = (float*)ws;               ws += (size_t)N_NODES * 64 * 4;   // 2.56 MB
    float* hx2 = (float*)ws;               ws += (size_t)N_NODES * 64 * 4;
    float* tp  = (float*)ws;               ws += (size_t)N_EDGES * 64 * 4;   // 16.4 MB (CSR order)
    float* hb2 = (float*)ws;               ws += (size_t)N_NODES * 64 * 4;
    float* agg = (float*)ws;               ws += (size_t)N_NODES * 64 * 4;
    float* hg  = (float*)ws;               ws += (size_t)N_GRAPHS * 64 * 4;  // 16 KB
    unsigned short* w2t1 = (unsigned short*)ws; ws += (size_t)64 * 64 * 64 * 2; // 512 KB
    unsigned short* w2t2 = (unsigned short*)ws; ws += (size_t)64 * 64 * 64 * 2; // 512 KB
    int* counts = (int*)ws;                ws += (size_t)10240 * 4;          // reused as cursor
    int* rowptr = (int*)ws;                ws += (size_t)10240 * 4;
    int* eidx   = (int*)ws;                ws += (size_t)N_EDGES * 4;
    int* dsts   = (int*)ws;                ws += (size_t)N_EDGES * 4;
    unsigned short* G = (unsigned short*)ws;  // 82 MB
    float* hx3 = hx1;

    dim3 blk(64, 4);

    // ---------- CSR by src + weight conversion (independent of data flow) ----------
    hipMemsetAsync(counts, 0, (size_t)N_NODES * 4, stream);
    csr_count_kernel<<<N_EDGES / 256, 256, 0, stream>>>(src, counts);
    csr_scan_kernel<<<1, 256, 0, stream>>>(counts, rowptr);
    hipMemsetAsync(counts, 0, (size_t)N_NODES * 4, stream);
    csr_scatter_kernel<<<N_EDGES / 256, 256, 0, stream>>>(src, dst, rowptr, counts, eidx, dsts);
    w2conv_kernel<<<128, 256, 0, stream>>>(e1w2, w2t1, e2w2, w2t2);

    // node FC
    lin64_kernel<128, 2><<<N_NODES / 4, blk, 0, stream>>>(x, nfc_w, nfc_b, hx1, N_NODES);

    dim3 ggrid((N_NODES + 63) / 64, 8);

    // ---------- layer 1 ----------
    lin64g_kernel<32, 1><<<N_EDGES / 4, blk, 0, stream>>>(ea, eidx, e1w1, e1b1, tp, N_EDGES);
    lin64_kernel<64, 0><<<N_NODES / 4, blk, 0, stream>>>(hx1, e1b2, nullptr, hb2, N_NODES);
    gmat_mfma_kernel<<<ggrid, 256, 0, stream>>>(hx1, w2t1, G);
    hipMemsetAsync(agg, 0, (size_t)N_NODES * 64 * 4, stream);
    msg_csr_kernel<<<N_NODES, 64, 0, stream>>>(tp, G, hb2, rowptr, dsts, agg);
    combine_kernel<<<N_NODES / 4, blk, 0, stream>>>(agg, hx1, g1root, g1bias, hx2, N_NODES);

    // ---------- layer 2 ----------
    lin64g_kernel<32, 1><<<N_EDGES / 4, blk, 0, stream>>>(ea, eidx, e2w1, e2b1, tp, N_EDGES);
    lin64_kernel<64, 0><<<N_NODES / 4, blk, 0, stream>>>(hx2, e2b2, nullptr, hb2, N_NODES);
    gmat_mfma_kernel<<<ggrid, 256, 0, stream>>>(hx2, w2t2, G);
    hipMemsetAsync(agg, 0, (size_t)N_NODES * 64 * 4, stream);
    msg_csr_kernel<<<N_NODES, 64, 0, stream>>>(tp, G, hb2, rowptr, dsts, agg);
    combine_kernel<<<N_NODES / 4, blk, 0, stream>>>(agg, hx2, g2root, g2bias, hx3, N_NODES);

    // ---------- pool + head ----------
    hipMemsetAsync(hg, 0, (size_t)N_GRAPHS * 64 * 4, stream);
    pool_kernel<<<N_NODES / 4, blk, 0, stream>>>(hx3, batch, hg, N_NODES);
    head_kernel<<<1, 64, 0, stream>>>(hg, fc1w, fc1b, fc2w, fc2b, out);
}

// Round 7
// 322.284 us; speedup vs baseline: 1.8680x; 1.0843x over previous
//
#include <hip/hip_runtime.h>
#include <hip/hip_bf16.h>

#define N_NODES  10000
#define N_EDGES  64000
#define N_GRAPHS 64
#define HID      64

typedef __attribute__((ext_vector_type(8))) short short8;
typedef __attribute__((ext_vector_type(4))) float f32x4;

__device__ __forceinline__ float lrelu(float v){ return v > 0.f ? v : 0.01f*v; }

__device__ __forceinline__ unsigned short f2bf(float f){
    union { float f; unsigned u; } v; v.f = f;
    unsigned r = v.u + 0x7fff + ((v.u >> 16) & 1);
    return (unsigned short)(r >> 16);
}
__device__ __forceinline__ float bf2f(unsigned short s){
    union { unsigned u; float f; } v; v.u = ((unsigned)s) << 16;
    return v.f;
}

// ---------------- preamble mega-kernel: nodeFC | w2conv(x2) | csr_count ----------------
#define PRE_NFC 2500
#define PRE_W2C 128
#define PRE_CNT 250
__global__ void __launch_bounds__(256) pre_kernel(
        const float* __restrict__ x, const float* __restrict__ nfc_w, const float* __restrict__ nfc_b,
        float* __restrict__ hx1,
        const float* __restrict__ e1w2, unsigned short* __restrict__ w2t1,
        const float* __restrict__ e2w2, unsigned short* __restrict__ w2t2,
        const int* __restrict__ src, int* __restrict__ counts){
    __shared__ float tile[64][65];
    int b = blockIdx.x, tid = threadIdx.x;
    if (b < PRE_NFC){
        int m = tid & 63, n = b * 4 + (tid >> 6);
        float acc = nfc_b[m];
        const float* row = x + (size_t)n * 128;
        #pragma unroll 8
        for (int k = 0; k < 128; ++k) acc += row[k] * nfc_w[k * 64 + m];
        hx1[(size_t)n * 64 + m] = lrelu(acc);
    } else if (b < PRE_NFC + PRE_W2C){
        int bb = b - PRE_NFC;
        int k = bb & 63;
        const float* srcw = ((bb < 64) ? e1w2 : e2w2) + (size_t)k * 4096;
        unsigned short* dstw = (bb < 64) ? w2t1 : w2t2;
        for (int idx = tid; idx < 4096; idx += 256) tile[idx >> 6][idx & 63] = srcw[idx];
        __syncthreads();
        for (int idx = tid; idx < 4096; idx += 256){
            int o = idx >> 6, i = idx & 63;
            dstw[((size_t)(k * 64 + o) << 6) + i] = f2bf(tile[i][o]);
        }
    } else {
        int e = (b - PRE_NFC - PRE_W2C) * 256 + tid;
        if (e < N_EDGES) atomicAdd(&counts[src[e]], 1);
    }
}

// scan rowptr from counts; also zero the scatter cursor (saves a fill launch)
__global__ void csr_scan_kernel(const int* __restrict__ counts, int* __restrict__ rowptr,
                                int* __restrict__ cursor){
    __shared__ int part[256];
    int tid = threadIdx.x;
    const int CH = (N_NODES + 255) / 256;      // 40
    int base = tid * CH, s = 0;
    for (int i = 0; i < CH; ++i){ int idx = base + i; if (idx < N_NODES){ cursor[idx] = 0; s += counts[idx]; } }
    part[tid] = s; __syncthreads();
    for (int off = 1; off < 256; off <<= 1){
        int v = (tid >= off) ? part[tid - off] : 0;
        __syncthreads();
        part[tid] += v;
        __syncthreads();
    }
    int run = part[tid] - s;
    for (int i = 0; i < CH; ++i){ int idx = base + i; if (idx < N_NODES){ rowptr[idx] = run; run += counts[idx]; } }
    if (tid == 255) rowptr[N_NODES] = run;
}

__global__ void csr_scatter_kernel(const int* __restrict__ src, const int* __restrict__ dst,
                                   const int* __restrict__ rowptr, int* __restrict__ cursor,
                                   int* __restrict__ eidx, int* __restrict__ dsts){
    int e = blockIdx.x * 256 + threadIdx.x;
    if (e >= N_EDGES) return;
    int s = src[e];
    int j = rowptr[s] + atomicAdd(&cursor[s], 1);
    eidx[j] = e; dsts[j] = dst[e];
}

// ---------------- per-layer mega-kernel: t-GEMM(bf16 out) | hb2+agg-zero | gmat | (hg-zero) ----
#define NBT 16000
#define NBH 2500
#define NBG (157 * 8)
template<int L2FLAG>
__global__ void __launch_bounds__(256) layerA_kernel(
        const float* __restrict__ ea, const int* __restrict__ eidx,
        const float* __restrict__ w1, const float* __restrict__ b1, unsigned short* __restrict__ tp,
        const float* __restrict__ hx, const float* __restrict__ b2m,
        float* __restrict__ hb2, float* __restrict__ agg,
        const unsigned short* __restrict__ w2t, unsigned short* __restrict__ G,
        float* __restrict__ hg){
    __shared__ unsigned short stg[64 * 256];   // 32 KB (gmat branch)
    int b = blockIdx.x, tid = threadIdx.x;
    if (b < NBT){
        // t[j,m] = bf16(relu(ea[eidx[j]] @ w1 + b1))   (CSR-ordered)
        int m = tid & 63, j = b * 4 + (tid >> 6);
        const float* row = ea + (size_t)eidx[j] * 32;
        float acc = b1[m];
        #pragma unroll
        for (int k = 0; k < 32; ++k) acc += row[k] * w1[k * 64 + m];
        tp[((size_t)j << 6) + m] = f2bf(fmaxf(acc, 0.f));
    } else if (b < NBT + NBH){
        // hb2[n,m] = hx[n] @ b2mat ; also zero agg row
        int m = tid & 63, n = (b - NBT) * 4 + (tid >> 6);
        const float* row = hx + (size_t)n * 64;
        float acc = 0.f;
        #pragma unroll 8
        for (int k = 0; k < 64; ++k) acc += row[k] * b2m[k * 64 + m];
        hb2[((size_t)n << 6) + m] = acc;
        agg[((size_t)n << 6) + m] = 0.f;
    } else if (b < NBT + NBH + NBG){
        // gmat: G[n, col] = sum_i hx[n,i] * w2t[col, i]  (swapped-operand MFMA, LDS-staged store)
        int g = b - NBT - NBH;
        int bx = g >> 3, by = g & 7;
        int wid = tid >> 6, l = tid & 63;
        int m16 = l & 15, grp = l >> 4;
        int n0 = bx * 64;
        int cb = by * 512;

        short8 bf0[4], bf1[4];
        #pragma unroll
        for (int ng = 0; ng < 4; ++ng){
            int node = n0 + ng * 16 + m16;
            short8 b0 = {0,0,0,0,0,0,0,0}, b1v = {0,0,0,0,0,0,0,0};
            if (node < N_NODES){
                const float* hp = hx + ((size_t)node << 6) + grp * 8;
                float4 f0 = *(const float4*)(hp);
                float4 f1 = *(const float4*)(hp + 4);
                float4 f2 = *(const float4*)(hp + 32);
                float4 f3 = *(const float4*)(hp + 36);
                b0[0]=(short)f2bf(f0.x); b0[1]=(short)f2bf(f0.y); b0[2]=(short)f2bf(f0.z); b0[3]=(short)f2bf(f0.w);
                b0[4]=(short)f2bf(f1.x); b0[5]=(short)f2bf(f1.y); b0[6]=(short)f2bf(f1.z); b0[7]=(short)f2bf(f1.w);
                b1v[0]=(short)f2bf(f2.x); b1v[1]=(short)f2bf(f2.y); b1v[2]=(short)f2bf(f2.z); b1v[3]=(short)f2bf(f2.w);
                b1v[4]=(short)f2bf(f3.x); b1v[5]=(short)f2bf(f3.y); b1v[6]=(short)f2bf(f3.z); b1v[7]=(short)f2bf(f3.w);
            }
            bf0[ng] = b0; bf1[ng] = b1v;
        }

        for (int h = 0; h < 2; ++h){
            #pragma unroll
            for (int tt = 0; tt < 4; ++tt){
                int t = h * 4 + tt;
                int TB = cb + t * 64 + wid * 16;
                const unsigned short* ap = w2t + ((size_t)(TB + m16) << 6) + grp * 8;
                short8 a0 = *(const short8*)ap;
                short8 a1 = *(const short8*)(ap + 32);
                int inrow = (tt * 128 + wid * 32 + grp * 8) ^ ((m16 & 7) << 4);
                #pragma unroll
                for (int ng = 0; ng < 4; ++ng){
                    f32x4 acc = {0.f, 0.f, 0.f, 0.f};
                    acc = __builtin_amdgcn_mfma_f32_16x16x32_bf16(a0, bf0[ng], acc, 0, 0, 0);
                    acc = __builtin_amdgcn_mfma_f32_16x16x32_bf16(a1, bf1[ng], acc, 0, 0, 0);
                    unsigned p0 = (unsigned)f2bf(acc[0]) | ((unsigned)f2bf(acc[1]) << 16);
                    unsigned p1 = (unsigned)f2bf(acc[2]) | ((unsigned)f2bf(acc[3]) << 16);
                    int row = ng * 16 + m16;
                    uint2 pk; pk.x = p0; pk.y = p1;
                    *(uint2*)((char*)stg + row * 512 + inrow) = pk;
                }
            }
            __syncthreads();
            #pragma unroll
            for (int s = 0; s < 8; ++s){
                int ci = s * 256 + tid;
                int row = ci >> 5;
                int node = n0 + row;
                uint4 v = *(uint4*)((char*)stg + row * 512 + (((ci & 31) * 16) ^ ((row & 7) << 4)));
                if (node < N_NODES)
                    *(uint4*)(G + ((size_t)node << 12) + cb + h * 256 + (ci & 31) * 8) = v;
            }
            __syncthreads();
        }
    } else if (L2FLAG){
        for (int i = tid; i < N_GRAPHS * 64; i += 256) hg[i] = 0.f;
    }
}

// ---------------- msg, grouped by src: G row streamed once; tp is bf16 CSR-ordered ----------
__global__ void __launch_bounds__(64) msg_csr_kernel(
        const unsigned short* __restrict__ tp, const unsigned short* __restrict__ G,
        const float* __restrict__ hb2, const int* __restrict__ rowptr,
        const int* __restrict__ dsts, float* __restrict__ agg){
    int s = blockIdx.x;
    int o = threadIdx.x;
    __shared__ unsigned short gl[4096];
    __shared__ unsigned short ts[64] __attribute__((aligned(16)));
    int r0 = rowptr[s], r1 = rowptr[s + 1];
    if (r0 == r1) return;                      // isolated node: agg row stays 0
    const short8* gsrc = (const short8*)(G + ((size_t)s << 12));
    short8* gld = (short8*)gl;
    #pragma unroll
    for (int i = 0; i < 8; ++i) gld[i * 64 + o] = gsrc[i * 64 + o];
    float g[64];
    #pragma unroll
    for (int k = 0; k < 64; ++k) g[k] = bf2f(gl[k * 64 + o]);
    float hb = hb2[((size_t)s << 6) + o];
    for (int j = r0; j < r1; ++j){
        ts[o] = tp[((size_t)j << 6) + o];
        float acc = hb;
        #pragma unroll
        for (int k8 = 0; k8 < 8; ++k8){
            short8 tv = *(const short8*)&ts[k8 * 8];
            #pragma unroll
            for (int u = 0; u < 8; ++u) acc += bf2f((unsigned short)tv[u]) * g[k8 * 8 + u];
        }
        atomicAdd(&agg[((size_t)dsts[j] << 6) + o], acc);
    }
}

// out[n,o] = lrelu(agg[n,o] + hx[n] @ root + bias)
__global__ void combine_kernel(const float* __restrict__ agg, const float* __restrict__ hx,
                               const float* __restrict__ root, const float* __restrict__ bias,
                               float* __restrict__ out, int N){
    int m = threadIdx.x;
    int n = blockIdx.x * 4 + threadIdx.y;
    if (n >= N) return;
    float acc = agg[(size_t)n * 64 + m] + bias[m];
    const float* row = hx + (size_t)n * 64;
    #pragma unroll 8
    for (int k = 0; k < 64; ++k) acc += row[k] * root[k * 64 + m];
    out[(size_t)n * 64 + m] = lrelu(acc);
}

// layer-2 combine fused with global_add_pool: atomicAdd(lrelu(row)) into hg
__global__ void combine2_kernel(const float* __restrict__ agg, const float* __restrict__ hx,
                                const float* __restrict__ root, const float* __restrict__ bias,
                                const int* __restrict__ batch, float* __restrict__ hg, int N){
    int m = threadIdx.x;
    int n = blockIdx.x * 4 + threadIdx.y;
    if (n >= N) return;
    float acc = agg[(size_t)n * 64 + m] + bias[m];
    const float* row = hx + (size_t)n * 64;
    #pragma unroll 8
    for (int k = 0; k < 64; ++k) acc += row[k] * root[k * 64 + m];
    atomicAdd(&hg[batch[n] * 64 + m], lrelu(acc));
}

__global__ void head_kernel(const float* __restrict__ hg, const float* __restrict__ fc1w,
                            const float* __restrict__ fc1b, const float* __restrict__ fc2w,
                            const float* __restrict__ fc2b, float* __restrict__ out){
    int g = threadIdx.x;                       // 0..63
    const float* row = hg + g * 64;
    float h1[32];
    #pragma unroll
    for (int j = 0; j < 32; ++j){
        float a = fc1b[j];
        #pragma unroll 8
        for (int i = 0; i < 64; ++i) a += row[i] * fc1w[i * 32 + j];
        h1[j] = lrelu(a);
    }
    float o = fc2b[0];
    #pragma unroll
    for (int j = 0; j < 32; ++j) o += h1[j] * fc2w[j];
    out[g] = o;
}

extern "C" void kernel_launch(void* const* d_in, const int* in_sizes, int n_in,
                              void* d_out, int out_size, void* d_ws, size_t ws_size,
                              hipStream_t stream){
    const float* x      = (const float*)d_in[0];
    const int*   ei     = (const int*)  d_in[1];
    const float* ea     = (const float*)d_in[2];
    const int*   batch  = (const int*)  d_in[3];
    const float* nfc_w  = (const float*)d_in[4];
    const float* nfc_b  = (const float*)d_in[5];
    const float* e1w1   = (const float*)d_in[6];
    const float* e1b1   = (const float*)d_in[7];
    const float* e1w2   = (const float*)d_in[8];
    const float* e1b2   = (const float*)d_in[9];
    const float* g1root = (const float*)d_in[10];
    const float* g1bias = (const float*)d_in[11];
    const float* e2w1   = (const float*)d_in[12];
    const float* e2b1   = (const float*)d_in[13];
    const float* e2w2   = (const float*)d_in[14];
    const float* e2b2   = (const float*)d_in[15];
    const float* g2root = (const float*)d_in[16];
    const float* g2bias = (const float*)d_in[17];
    const float* fc1w   = (const float*)d_in[18];
    const float* fc1b   = (const float*)d_in[19];
    const float* fc2w   = (const float*)d_in[20];
    const float* fc2b   = (const float*)d_in[21];
    float* out = (float*)d_out;

    const int* src = ei;
    const int* dst = ei + N_EDGES;

    // workspace carve-up
    char* ws = (char*)d_ws;
    float* hx1 = (float*)ws;               ws += (size_t)N_NODES * 64 * 4;
    float* hx2 = (float*)ws;               ws += (size_t)N_NODES * 64 * 4;
    unsigned short* tp = (unsigned short*)ws; ws += (size_t)N_EDGES * 64 * 2;  // 8.2 MB bf16, CSR order
    float* hb2 = (float*)ws;               ws += (size_t)N_NODES * 64 * 4;
    float* agg = (float*)ws;               ws += (size_t)N_NODES * 64 * 4;
    float* hg  = (float*)ws;               ws += (size_t)N_GRAPHS * 64 * 4;
    unsigned short* w2t1 = (unsigned short*)ws; ws += (size_t)64 * 64 * 64 * 2;
    unsigned short* w2t2 = (unsigned short*)ws; ws += (size_t)64 * 64 * 64 * 2;
    int* counts = (int*)ws;                ws += (size_t)10240 * 4;
    int* cursor = (int*)ws;                ws += (size_t)10240 * 4;
    int* rowptr = (int*)ws;                ws += (size_t)10240 * 4;
    int* eidx   = (int*)ws;                ws += (size_t)N_EDGES * 4;
    int* dsts   = (int*)ws;                ws += (size_t)N_EDGES * 4;
    unsigned short* G = (unsigned short*)ws;  // 82 MB

    dim3 blk(64, 4);

    // 1: zero counts; 2: nodeFC | w2conv | csr_count; 3: scan(+cursor0); 4: scatter
    hipMemsetAsync(counts, 0, (size_t)N_NODES * 4, stream);
    pre_kernel<<<PRE_NFC + PRE_W2C + PRE_CNT, 256, 0, stream>>>(
        x, nfc_w, nfc_b, hx1, e1w2, w2t1, e2w2, w2t2, src, counts);
    csr_scan_kernel<<<1, 256, 0, stream>>>(counts, rowptr, cursor);
    csr_scatter_kernel<<<N_EDGES / 256, 256, 0, stream>>>(src, dst, rowptr, cursor, eidx, dsts);

    // ---------- layer 1 (5,6,7) ----------
    layerA_kernel<0><<<NBT + NBH + NBG, 256, 0, stream>>>(
        ea, eidx, e1w1, e1b1, tp, hx1, e1b2, hb2, agg, w2t1, G, nullptr);
    msg_csr_kernel<<<N_NODES, 64, 0, stream>>>(tp, G, hb2, rowptr, dsts, agg);
    combine_kernel<<<N_NODES / 4, blk, 0, stream>>>(agg, hx1, g1root, g1bias, hx2, N_NODES);

    // ---------- layer 2 (8,9,10) ----------
    layerA_kernel<1><<<NBT + NBH + NBG + 1, 256, 0, stream>>>(
        ea, eidx, e2w1, e2b1, tp, hx2, e2b2, hb2, agg, w2t2, G, hg);
    msg_csr_kernel<<<N_NODES, 64, 0, stream>>>(tp, G, hb2, rowptr, dsts, agg);
    combine2_kernel<<<N_NODES / 4, blk, 0, stream>>>(agg, hx2, g2root, g2bias, batch, hg, N_NODES);

    // 11: head
    head_kernel<<<1, 64, 0, stream>>>(hg, fc1w, fc1b, fc2w, fc2b, out);
}